// Round 2
// baseline (1817.082 us; speedup 1.0000x reference)
//
#include <hip/hip_runtime.h>
#include <hip/hip_bf16.h>
#include <math.h>

// Problem constants (Qwen3 MoE experts)
#define E_N 32
#define H_N 1024
#define I_N 768
#define T_N 2048
#define K_N 8
#define MT  16                         // M-tile: slots per expert tile
#define NPAIRS (T_N * K_N)             // 16384 (t,k) pairs
#define MAX_SLOTS (NPAIRS + E_N * MT)  // 16896 padded slots (worst case)
#define MAX_TILES (NPAIRS / MT + E_N)  // 1056 tiles (worst case)

typedef __attribute__((ext_vector_type(8))) short bf16x8;  // 8 bf16 = 4 VGPRs
typedef __attribute__((ext_vector_type(8))) float f32x8;
typedef __attribute__((ext_vector_type(4))) float f32x4;

// fp32 -> bf16 (RNE) on an 8-vector, in-register
__device__ inline bf16x8 cvt_bf16x8(f32x8 v) {
    bf16x8 r;
#pragma unroll
    for (int i = 0; i < 8; ++i) {
        union { float f; unsigned u; } w;
        w.f = v[i];
        unsigned lsb = (w.u >> 16) & 1u;
        w.u += 0x7fffu + lsb;
        r[i] = (short)(w.u >> 16);
    }
    return r;
}

// ---------------------------------------------------------------------------
// Kernel 1: routing. Bucket (t,k) pairs by expert, pad each expert segment to
// a multiple of MT, build tile descriptor table. Single block.
// ---------------------------------------------------------------------------
__global__ void route_kernel(const int* __restrict__ sel,
                             int* __restrict__ slot_token,
                             int* __restrict__ pair_slot,
                             int* __restrict__ tile_expert,
                             int* __restrict__ tile_row0,
                             int* __restrict__ n_tiles_out) {
    __shared__ int cnt[E_N], off[E_N], cur[E_N];
    int tid = threadIdx.x;
    if (tid < E_N) cnt[tid] = 0;
    __syncthreads();
    for (int p = tid; p < NPAIRS; p += blockDim.x)
        atomicAdd(&cnt[sel[p]], 1);
    __syncthreads();
    if (tid == 0) {
        int acc = 0, tt = 0;
        for (int e = 0; e < E_N; ++e) {
            off[e] = acc;
            cur[e] = 0;
            int nt = (cnt[e] + MT - 1) / MT;
            for (int i = 0; i < nt; ++i) {
                tile_expert[tt] = e;
                tile_row0[tt] = acc + i * MT;
                ++tt;
            }
            acc += nt * MT;
        }
        *n_tiles_out = tt;
    }
    __syncthreads();
    for (int s = tid; s < MAX_SLOTS; s += blockDim.x) slot_token[s] = -1;
    __syncthreads();
    for (int p = tid; p < NPAIRS; p += blockDim.x) {
        int e = sel[p];
        int slot = off[e] + atomicAdd(&cur[e], 1);
        slot_token[slot] = p / K_N;  // token index
        pair_slot[p] = slot;
    }
}

// ---------------------------------------------------------------------------
// Kernel 2: gate/up GEMM + SwiGLU. fp32 inputs, bf16 MFMA compute.
// Per block: one 16-row slot tile x 64 columns of I. 4 waves; each wave owns
// 16 columns, computing G and U 16x16 accumulators over K=H.
// NT layout: A-frag lane m=lane&15 loads 8 contiguous elems of its token row;
// B-frag lane n=lane&15 loads 8 contiguous elems of weight row (n0+n).
// ---------------------------------------------------------------------------
__global__ __launch_bounds__(256) void gateup_kernel(
    const float* __restrict__ hs,
    const float* __restrict__ gate,
    const float* __restrict__ up,
    const int* __restrict__ slot_token,
    const int* __restrict__ tile_expert,
    const int* __restrict__ tile_row0,
    const int* __restrict__ n_tiles,
    __hip_bfloat16* __restrict__ h_buf) {
    int tile = blockIdx.x;
    if (tile >= *n_tiles) return;
    int e = tile_expert[tile];
    int row0 = tile_row0[tile];
    int wave = threadIdx.x >> 6;
    int lane = threadIdx.x & 63;
    int quad = lane >> 4;
    int r16 = lane & 15;
    int n0 = blockIdx.y * 64 + wave * 16;  // column base in I

    int tok = slot_token[row0 + r16];
    bool valid = (tok >= 0);
    const float* arow = hs + (size_t)(valid ? tok : 0) * H_N;  // clamped: always a valid address
    const float* grow = gate + (size_t)e * I_N * H_N + (size_t)(n0 + r16) * H_N;
    const float* urow = up   + (size_t)e * I_N * H_N + (size_t)(n0 + r16) * H_N;

    const bf16x8 zfrag = {0, 0, 0, 0, 0, 0, 0, 0};
    f32x4 accG = {0.f, 0.f, 0.f, 0.f};
    f32x4 accU = {0.f, 0.f, 0.f, 0.f};

    for (int k0 = quad * 8; k0 < H_N; k0 += 32) {
        bf16x8 a = cvt_bf16x8(*(const f32x8*)(arow + k0));
        if (!valid) a = zfrag;  // mask value, not the load
        bf16x8 bg = cvt_bf16x8(*(const f32x8*)(grow + k0));
        bf16x8 bu = cvt_bf16x8(*(const f32x8*)(urow + k0));
        accG = __builtin_amdgcn_mfma_f32_16x16x32_bf16(a, bg, accG, 0, 0, 0);
        accU = __builtin_amdgcn_mfma_f32_16x16x32_bf16(a, bu, accU, 0, 0, 0);
    }
    // C/D layout: col(n)=lane&15, row(m)=quad*4+reg  [measured m89/m91]
    for (int r = 0; r < 4; ++r) {
        int m = quad * 4 + r;
        float g = accG[r], u = accU[r];
        float hval = g * u / (1.0f + __expf(-g));  // silu(g)*u
        h_buf[(size_t)(row0 + m) * I_N + (n0 + r16)] = __float2bfloat16(hval);
    }
}

// ---------------------------------------------------------------------------
// Kernel 3: down GEMM. A = h_buf tile (bf16; pad rows are exact zeros),
// B = down[e] rows (fp32 -> bf16), K = I = 768. fp32 output rows.
// ---------------------------------------------------------------------------
__global__ __launch_bounds__(256) void down_kernel(
    const __hip_bfloat16* __restrict__ h_buf,
    const float* __restrict__ down,
    const int* __restrict__ tile_expert,
    const int* __restrict__ tile_row0,
    const int* __restrict__ n_tiles,
    float* __restrict__ d_buf) {
    int tile = blockIdx.x;
    if (tile >= *n_tiles) return;
    int e = tile_expert[tile];
    int row0 = tile_row0[tile];
    int wave = threadIdx.x >> 6;
    int lane = threadIdx.x & 63;
    int quad = lane >> 4;
    int r16 = lane & 15;
    int n0 = blockIdx.y * 64 + wave * 16;  // column base in H

    const short* arow = (const short*)h_buf + (size_t)(row0 + r16) * I_N;
    const float* brow = down + (size_t)e * H_N * I_N + (size_t)(n0 + r16) * I_N;

    f32x4 acc = {0.f, 0.f, 0.f, 0.f};
    for (int k0 = quad * 8; k0 < I_N; k0 += 32) {
        bf16x8 a = *(const bf16x8*)(arow + k0);
        bf16x8 b = cvt_bf16x8(*(const f32x8*)(brow + k0));
        acc = __builtin_amdgcn_mfma_f32_16x16x32_bf16(a, b, acc, 0, 0, 0);
    }
    for (int r = 0; r < 4; ++r) {
        int m = quad * 4 + r;
        d_buf[(size_t)(row0 + m) * H_N + (n0 + r16)] = acc[r];
    }
}

// ---------------------------------------------------------------------------
// Kernel 4: combine. out[t,h] = sum_k rw[t,k] * d_buf[pair_slot[t,k], h].
// Deterministic gather (no atomics). fp32 I/O.
// ---------------------------------------------------------------------------
__global__ __launch_bounds__(256) void combine_kernel(
    const float* __restrict__ d_buf,
    const int* __restrict__ pair_slot,
    const float* __restrict__ rw,
    float* __restrict__ out) {
    int idx = blockIdx.x * blockDim.x + threadIdx.x;
    int t = idx >> 10;          // H_N = 1024
    int h = idx & (H_N - 1);
    float acc = 0.f;
#pragma unroll
    for (int k = 0; k < K_N; ++k) {
        int slot = pair_slot[t * K_N + k];
        float w = rw[t * K_N + k];
        acc += w * d_buf[(size_t)slot * H_N + h];
    }
    out[idx] = acc;
}

// ---------------------------------------------------------------------------
extern "C" void kernel_launch(void* const* d_in, const int* in_sizes, int n_in,
                              void* d_out, int out_size, void* d_ws, size_t ws_size,
                              hipStream_t stream) {
    const float* hs   = (const float*)d_in[0];
    const float* rw   = (const float*)d_in[1];
    const int*   sel  = (const int*)d_in[2];
    const float* gate = (const float*)d_in[3];
    const float* up   = (const float*)d_in[4];
    const float* down = (const float*)d_in[5];
    float* out = (float*)d_out;

    // Workspace carve-up (all offsets 256B-aligned)
    char* ws = (char*)d_ws;
    int* slot_token  = (int*)ws;  ws += ((size_t)MAX_SLOTS * 4 + 255) / 256 * 256;
    int* pair_slot   = (int*)ws;  ws += ((size_t)NPAIRS * 4 + 255) / 256 * 256;
    int* tile_expert = (int*)ws;  ws += ((size_t)MAX_TILES * 4 + 255) / 256 * 256;
    int* tile_row0   = (int*)ws;  ws += ((size_t)MAX_TILES * 4 + 255) / 256 * 256;
    int* n_tiles     = (int*)ws;  ws += 256;
    __hip_bfloat16* h_buf = (__hip_bfloat16*)ws;
    ws += ((size_t)MAX_SLOTS * I_N * 2 + 255) / 256 * 256;
    float* d_buf = (float*)ws;
    // total ~95.3 MB of d_ws

    route_kernel<<<1, 256, 0, stream>>>(sel, slot_token, pair_slot,
                                        tile_expert, tile_row0, n_tiles);

    dim3 grid_gu(MAX_TILES, I_N / 64);
    gateup_kernel<<<grid_gu, 256, 0, stream>>>(hs, gate, up, slot_token,
                                               tile_expert, tile_row0, n_tiles,
                                               h_buf);

    dim3 grid_dn(MAX_TILES, H_N / 64);
    down_kernel<<<grid_dn, 256, 0, stream>>>(h_buf, down, tile_expert,
                                             tile_row0, n_tiles, d_buf);

    combine_kernel<<<(T_N * H_N) / 256, 256, 0, stream>>>(d_buf, pair_slot,
                                                          rw, out);
}

// Round 3
// 521.657 us; speedup vs baseline: 3.4833x; 3.4833x over previous
//
#include <hip/hip_runtime.h>
#include <hip/hip_bf16.h>
#include <math.h>

// Problem constants (Qwen3 MoE experts)
#define E_N 32
#define H_N 1024
#define I_N 768
#define T_N 2048
#define K_N 8
#define MT  128                        // M-tile: slots per expert tile
#define NPAIRS (T_N * K_N)             // 16384 (t,k) pairs
#define MAX_SLOTS (NPAIRS + E_N * MT)  // 20480 padded slots (worst case)
#define MAX_TILES (NPAIRS / MT + E_N)  // 160 tiles (worst case)

typedef __attribute__((ext_vector_type(8))) short bf16x8;  // 8 bf16 = 4 VGPRs
typedef __attribute__((ext_vector_type(4))) short bf16x4;
typedef __attribute__((ext_vector_type(8))) float f32x8;
typedef __attribute__((ext_vector_type(4))) float f32x4;

// pack two fp32 -> two bf16 (round-half-up: ~0.5 ulp, 3 VALU)
__device__ __forceinline__ unsigned pk2(float a, float b) {
    unsigned ua = __float_as_uint(a) + 0x8000u;
    unsigned ub = __float_as_uint(b) + 0x8000u;
    return (ua >> 16) | (ub & 0xffff0000u);
}
__device__ __forceinline__ bf16x8 cvt8(f32x8 v) {
    union { unsigned u[4]; bf16x8 h; } r;
    r.u[0] = pk2(v[0], v[1]); r.u[1] = pk2(v[2], v[3]);
    r.u[2] = pk2(v[4], v[5]); r.u[3] = pk2(v[6], v[7]);
    return r.h;
}
__device__ __forceinline__ float bf2f(short s) {
    return __uint_as_float(((unsigned)(unsigned short)s) << 16);
}

// ---------------------------------------------------------------------------
// Kernel 1: routing. Bucket (t,k) pairs by expert, pad to MT=128, build tile
// table. slot_token pre-initialized to -1 via hipMemsetAsync(0xFF).
// ---------------------------------------------------------------------------
__global__ void route_kernel(const int* __restrict__ sel,
                             int* __restrict__ slot_token,
                             int* __restrict__ pair_slot,
                             int* __restrict__ tile_expert,
                             int* __restrict__ tile_row0,
                             int* __restrict__ n_tiles_out) {
    __shared__ int cnt[E_N], off[E_N], cur[E_N];
    int tid = threadIdx.x;
    if (tid < E_N) cnt[tid] = 0;
    __syncthreads();
    for (int p = tid; p < NPAIRS; p += blockDim.x)
        atomicAdd(&cnt[sel[p]], 1);
    __syncthreads();
    if (tid == 0) {
        int acc = 0, tt = 0;
        for (int e = 0; e < E_N; ++e) {
            off[e] = acc;
            cur[e] = 0;
            int nt = (cnt[e] + MT - 1) / MT;
            for (int i = 0; i < nt; ++i) {
                tile_expert[tt] = e;
                tile_row0[tt] = acc + i * MT;
                ++tt;
            }
            acc += nt * MT;
        }
        *n_tiles_out = tt;
    }
    __syncthreads();
    for (int p = tid; p < NPAIRS; p += blockDim.x) {
        int e = sel[p];
        int slot = off[e] + atomicAdd(&cur[e], 1);
        slot_token[slot] = p / K_N;  // token index
        pair_slot[p] = slot;
    }
}

// ---------------------------------------------------------------------------
// Kernel 2: gather tokens -> contiguous bf16 x_buf[slot][H]; pad slots = 0.
// ---------------------------------------------------------------------------
__global__ __launch_bounds__(256) void gather_kernel(
    const float* __restrict__ hs,
    const int* __restrict__ slot_token,
    short* __restrict__ x_buf) {
    int idx = blockIdx.x * 256 + threadIdx.x;   // one thread per 4 elems
    int slot = idx >> 8;                        // H_N/4 = 256 threads/slot
    int pos = (idx & 255) * 4;
    int tok = slot_token[slot];
    union { unsigned u[2]; bf16x4 s; } o;
    if (tok >= 0) {
        f32x4 v = *(const f32x4*)(hs + (size_t)tok * H_N + pos);
        o.u[0] = pk2(v[0], v[1]);
        o.u[1] = pk2(v[2], v[3]);
    } else {
        o.u[0] = 0; o.u[1] = 0;
    }
    *(bf16x4*)(x_buf + (size_t)slot * H_N + pos) = o.s;
}

// ---------------------------------------------------------------------------
// Kernel 3: gate/up GEMM + SwiGLU. 128x128 block tile, 4 waves (2x2), each
// wave 64x64 for BOTH G and U (shared A). BK=32, 2-barrier K-loop, LDS-staged
// bf16 tiles (weights converted fp32->bf16 during staging).
// ---------------------------------------------------------------------------
__global__ __launch_bounds__(256, 2) void gateup_kernel(
    const short* __restrict__ x_buf,
    const float* __restrict__ gate,
    const float* __restrict__ up,
    const int* __restrict__ tile_expert,
    const int* __restrict__ tile_row0,
    const int* __restrict__ n_tiles,
    __hip_bfloat16* __restrict__ h_buf) {
    int tile = blockIdx.x;
    if (tile >= *n_tiles) return;
    __shared__ short sA[128 * 32];
    __shared__ short sG[128 * 32];
    __shared__ short sU[128 * 32];
    int e = tile_expert[tile];
    int row0 = tile_row0[tile];
    int col0 = blockIdx.y * 128;  // in I
    int tid = threadIdx.x;
    int wave = tid >> 6, lane = tid & 63, quad = lane >> 4, r16 = lane & 15;
    int m0w = (wave >> 1) * 64, n0w = (wave & 1) * 64;
    int srow = tid >> 2;          // staging: 0..63
    int scol = (tid & 3) * 8;     // elem offset in K-chunk

    f32x4 accG[4][4], accU[4][4];
#pragma unroll
    for (int i = 0; i < 4; ++i)
#pragma unroll
        for (int j = 0; j < 4; ++j) {
            accG[i][j] = (f32x4){0.f, 0.f, 0.f, 0.f};
            accU[i][j] = (f32x4){0.f, 0.f, 0.f, 0.f};
        }

    const size_t gbase = ((size_t)e * I_N + col0) * H_N;

#pragma unroll 1
    for (int k0 = 0; k0 < H_N; k0 += 32) {
        __syncthreads();  // prior iter's frag reads done before overwrite
#pragma unroll
        for (int r = 0; r < 2; ++r) {
            int row = r * 64 + srow;
            bf16x8 av = *(const bf16x8*)(x_buf + (size_t)(row0 + row) * H_N + k0 + scol);
            *(bf16x8*)&sA[row * 32 + scol] = av;
            f32x8 gv = *(const f32x8*)(gate + gbase + (size_t)row * H_N + k0 + scol);
            *(bf16x8*)&sG[row * 32 + scol] = cvt8(gv);
            f32x8 uv = *(const f32x8*)(up + gbase + (size_t)row * H_N + k0 + scol);
            *(bf16x8*)&sU[row * 32 + scol] = cvt8(uv);
        }
        __syncthreads();
        bf16x8 af[4], bg[4], bu[4];
#pragma unroll
        for (int mi = 0; mi < 4; ++mi)
            af[mi] = *(const bf16x8*)&sA[(m0w + mi * 16 + r16) * 32 + quad * 8];
#pragma unroll
        for (int ni = 0; ni < 4; ++ni) {
            bg[ni] = *(const bf16x8*)&sG[(n0w + ni * 16 + r16) * 32 + quad * 8];
            bu[ni] = *(const bf16x8*)&sU[(n0w + ni * 16 + r16) * 32 + quad * 8];
        }
#pragma unroll
        for (int mi = 0; mi < 4; ++mi)
#pragma unroll
            for (int ni = 0; ni < 4; ++ni) {
                accG[mi][ni] = __builtin_amdgcn_mfma_f32_16x16x32_bf16(af[mi], bg[ni], accG[mi][ni], 0, 0, 0);
                accU[mi][ni] = __builtin_amdgcn_mfma_f32_16x16x32_bf16(af[mi], bu[ni], accU[mi][ni], 0, 0, 0);
            }
    }
    // C/D layout: col(n)=lane&15, row(m)=quad*4+reg  [verified round 2]
#pragma unroll
    for (int mi = 0; mi < 4; ++mi)
#pragma unroll
        for (int ni = 0; ni < 4; ++ni)
#pragma unroll
            for (int r = 0; r < 4; ++r) {
                int m = m0w + mi * 16 + quad * 4 + r;
                int n = col0 + n0w + ni * 16 + r16;
                float g = accG[mi][ni][r], u = accU[mi][ni][r];
                float hval = g * u / (1.0f + __expf(-g));
                h_buf[(size_t)(row0 + m) * I_N + n] = __float2bfloat16(hval);
            }
}

// ---------------------------------------------------------------------------
// Kernel 4: down GEMM. 128x128 tile, wave 64x64, BK=32, K=I=768.
// A = h_buf bf16, B = down fp32->bf16 staged. Output bf16 into d_buf.
// ---------------------------------------------------------------------------
__global__ __launch_bounds__(256, 2) void down_kernel(
    const __hip_bfloat16* __restrict__ h_buf,
    const float* __restrict__ down,
    const int* __restrict__ tile_expert,
    const int* __restrict__ tile_row0,
    const int* __restrict__ n_tiles,
    short* __restrict__ d_buf) {
    int tile = blockIdx.x;
    if (tile >= *n_tiles) return;
    __shared__ short sA[128 * 32];
    __shared__ short sB[128 * 32];
    int e = tile_expert[tile];
    int row0 = tile_row0[tile];
    int col0 = blockIdx.y * 128;  // in H
    int tid = threadIdx.x;
    int wave = tid >> 6, lane = tid & 63, quad = lane >> 4, r16 = lane & 15;
    int m0w = (wave >> 1) * 64, n0w = (wave & 1) * 64;
    int srow = tid >> 2;
    int scol = (tid & 3) * 8;

    f32x4 acc[4][4];
#pragma unroll
    for (int i = 0; i < 4; ++i)
#pragma unroll
        for (int j = 0; j < 4; ++j) acc[i][j] = (f32x4){0.f, 0.f, 0.f, 0.f};

    const short* hb = (const short*)h_buf;
    const size_t dbase = ((size_t)e * H_N + col0) * I_N;

#pragma unroll 1
    for (int k0 = 0; k0 < I_N; k0 += 32) {
        __syncthreads();
#pragma unroll
        for (int r = 0; r < 2; ++r) {
            int row = r * 64 + srow;
            bf16x8 av = *(const bf16x8*)(hb + (size_t)(row0 + row) * I_N + k0 + scol);
            *(bf16x8*)&sA[row * 32 + scol] = av;
            f32x8 bv = *(const f32x8*)(down + dbase + (size_t)row * I_N + k0 + scol);
            *(bf16x8*)&sB[row * 32 + scol] = cvt8(bv);
        }
        __syncthreads();
        bf16x8 af[4], bf[4];
#pragma unroll
        for (int mi = 0; mi < 4; ++mi)
            af[mi] = *(const bf16x8*)&sA[(m0w + mi * 16 + r16) * 32 + quad * 8];
#pragma unroll
        for (int ni = 0; ni < 4; ++ni)
            bf[ni] = *(const bf16x8*)&sB[(n0w + ni * 16 + r16) * 32 + quad * 8];
#pragma unroll
        for (int mi = 0; mi < 4; ++mi)
#pragma unroll
            for (int ni = 0; ni < 4; ++ni)
                acc[mi][ni] = __builtin_amdgcn_mfma_f32_16x16x32_bf16(af[mi], bf[ni], acc[mi][ni], 0, 0, 0);
    }
#pragma unroll
    for (int mi = 0; mi < 4; ++mi)
#pragma unroll
        for (int ni = 0; ni < 4; ++ni)
#pragma unroll
            for (int r = 0; r < 4; ++r) {
                int m = m0w + mi * 16 + quad * 4 + r;
                int n = col0 + n0w + ni * 16 + r16;
                unsigned u = __float_as_uint(acc[mi][ni][r]) + 0x8000u;
                d_buf[(size_t)(row0 + m) * H_N + n] = (short)(u >> 16);
            }
}

// ---------------------------------------------------------------------------
// Kernel 5: combine. out[t,h] = sum_k rw[t,k] * d_buf[pair_slot[t,k], h].
// ---------------------------------------------------------------------------
__global__ __launch_bounds__(256) void combine_kernel(
    const short* __restrict__ d_buf,
    const int* __restrict__ pair_slot,
    const float* __restrict__ rw,
    float* __restrict__ out) {
    int idx = blockIdx.x * blockDim.x + threadIdx.x;
    int t = idx >> 10;          // H_N = 1024
    int h = idx & (H_N - 1);
    float acc = 0.f;
#pragma unroll
    for (int k = 0; k < K_N; ++k) {
        int slot = pair_slot[t * K_N + k];
        float w = rw[t * K_N + k];
        acc += w * bf2f(d_buf[(size_t)slot * H_N + h]);
    }
    out[idx] = acc;
}

// ---------------------------------------------------------------------------
extern "C" void kernel_launch(void* const* d_in, const int* in_sizes, int n_in,
                              void* d_out, int out_size, void* d_ws, size_t ws_size,
                              hipStream_t stream) {
    const float* hs   = (const float*)d_in[0];
    const float* rw   = (const float*)d_in[1];
    const int*   sel  = (const int*)d_in[2];
    const float* gate = (const float*)d_in[3];
    const float* up   = (const float*)d_in[4];
    const float* down = (const float*)d_in[5];
    float* out = (float*)d_out;

    // Workspace carve-up (256B-aligned). x_buf reused as d_buf (both
    // MAX_SLOTS x H_N bf16; x dead after gateup). Total ~74 MB.
    char* ws = (char*)d_ws;
    int* slot_token  = (int*)ws;  ws += ((size_t)MAX_SLOTS * 4 + 255) / 256 * 256;
    int* pair_slot   = (int*)ws;  ws += ((size_t)NPAIRS * 4 + 255) / 256 * 256;
    int* tile_expert = (int*)ws;  ws += ((size_t)MAX_TILES * 4 + 255) / 256 * 256;
    int* tile_row0   = (int*)ws;  ws += ((size_t)MAX_TILES * 4 + 255) / 256 * 256;
    int* n_tiles     = (int*)ws;  ws += 256;
    short* x_buf = (short*)ws;    ws += ((size_t)MAX_SLOTS * H_N * 2 + 255) / 256 * 256;
    __hip_bfloat16* h_buf = (__hip_bfloat16*)ws;
    short* d_buf = x_buf;  // reuse

    hipMemsetAsync(slot_token, 0xFF, (size_t)MAX_SLOTS * 4, stream);
    route_kernel<<<1, 256, 0, stream>>>(sel, slot_token, pair_slot,
                                        tile_expert, tile_row0, n_tiles);
    gather_kernel<<<(MAX_SLOTS * H_N / 4) / 256, 256, 0, stream>>>(hs, slot_token, x_buf);

    dim3 grid_gu(MAX_TILES, I_N / 128);
    gateup_kernel<<<grid_gu, 256, 0, stream>>>(x_buf, gate, up, tile_expert,
                                               tile_row0, n_tiles, h_buf);

    dim3 grid_dn(MAX_TILES, H_N / 128);
    down_kernel<<<grid_dn, 256, 0, stream>>>(h_buf, down, tile_expert,
                                             tile_row0, n_tiles, d_buf);

    combine_kernel<<<(T_N * H_N) / 256, 256, 0, stream>>>(d_buf, pair_slot,
                                                          rw, out);
}

// Round 4
// 495.577 us; speedup vs baseline: 3.6666x; 1.0526x over previous
//
#include <hip/hip_runtime.h>
#include <hip/hip_bf16.h>
#include <math.h>

// Problem constants (Qwen3 MoE experts)
#define E_N 32
#define H_N 1024
#define I_N 768
#define T_N 2048
#define K_N 8
#define MT  128                        // M-tile: slots per expert tile
#define NPAIRS (T_N * K_N)             // 16384 (t,k) pairs
#define MAX_SLOTS (NPAIRS + E_N * MT)  // 20480 padded slots (worst case)
#define MAX_TILES (NPAIRS / MT + E_N)  // 160 tiles (worst case)
#define RS 40                          // LDS row stride in shorts (pad 32->40: 2-way only)

typedef __attribute__((ext_vector_type(8))) short bf16x8;  // 8 bf16 = 4 VGPRs
typedef __attribute__((ext_vector_type(4))) short bf16x4;
typedef __attribute__((ext_vector_type(8))) float f32x8;
typedef __attribute__((ext_vector_type(4))) float f32x4;

// pack two fp32 -> two bf16 (round-half-up: ~0.5 ulp, 3 VALU)
__device__ __forceinline__ unsigned pk2(float a, float b) {
    unsigned ua = __float_as_uint(a) + 0x8000u;
    unsigned ub = __float_as_uint(b) + 0x8000u;
    return (ua >> 16) | (ub & 0xffff0000u);
}
__device__ __forceinline__ bf16x8 cvt8(f32x8 v) {
    union { unsigned u[4]; bf16x8 h; } r;
    r.u[0] = pk2(v[0], v[1]); r.u[1] = pk2(v[2], v[3]);
    r.u[2] = pk2(v[4], v[5]); r.u[3] = pk2(v[6], v[7]);
    return r.h;
}
__device__ __forceinline__ float bf2f(short s) {
    return __uint_as_float(((unsigned)(unsigned short)s) << 16);
}

// ---------------------------------------------------------------------------
// Kernel 1: routing. Bucket (t,k) pairs by expert, pad to MT=128, build tile
// table. slot_token pre-initialized to -1 via hipMemsetAsync(0xFF).
// ---------------------------------------------------------------------------
__global__ void route_kernel(const int* __restrict__ sel,
                             int* __restrict__ slot_token,
                             int* __restrict__ pair_slot,
                             int* __restrict__ tile_expert,
                             int* __restrict__ tile_row0,
                             int* __restrict__ n_tiles_out) {
    __shared__ int cnt[E_N], off[E_N], cur[E_N];
    int tid = threadIdx.x;
    if (tid < E_N) cnt[tid] = 0;
    __syncthreads();
    for (int p = tid; p < NPAIRS; p += blockDim.x)
        atomicAdd(&cnt[sel[p]], 1);
    __syncthreads();
    if (tid == 0) {
        int acc = 0, tt = 0;
        for (int e = 0; e < E_N; ++e) {
            off[e] = acc;
            cur[e] = 0;
            int nt = (cnt[e] + MT - 1) / MT;
            for (int i = 0; i < nt; ++i) {
                tile_expert[tt] = e;
                tile_row0[tt] = acc + i * MT;
                ++tt;
            }
            acc += nt * MT;
        }
        *n_tiles_out = tt;
    }
    __syncthreads();
    for (int p = tid; p < NPAIRS; p += blockDim.x) {
        int e = sel[p];
        int slot = off[e] + atomicAdd(&cur[e], 1);
        slot_token[slot] = p / K_N;  // token index
        pair_slot[p] = slot;
    }
}

// ---------------------------------------------------------------------------
// Kernel 2: gather tokens -> contiguous bf16 x_buf[slot][H]; pad slots = 0.
// ---------------------------------------------------------------------------
__global__ __launch_bounds__(256) void gather_kernel(
    const float* __restrict__ hs,
    const int* __restrict__ slot_token,
    short* __restrict__ x_buf) {
    int idx = blockIdx.x * 256 + threadIdx.x;   // one thread per 4 elems
    int slot = idx >> 8;                        // H_N/4 = 256 threads/slot
    int pos = (idx & 255) * 4;
    int tok = slot_token[slot];
    union { unsigned u[2]; bf16x4 s; } o;
    if (tok >= 0) {
        f32x4 v = *(const f32x4*)(hs + (size_t)tok * H_N + pos);
        o.u[0] = pk2(v[0], v[1]);
        o.u[1] = pk2(v[2], v[3]);
    } else {
        o.u[0] = 0; o.u[1] = 0;
    }
    *(bf16x4*)(x_buf + (size_t)slot * H_N + pos) = o.s;
}

// ---------------------------------------------------------------------------
// Kernel 3: gate/up GEMM + SwiGLU. 128x128 tile, 4 waves (2x2), wave 64x64
// for BOTH G and U (shared A). BK=32. Register-prefetch pipeline: iter k+1's
// global loads issue before iter k's MFMA phase so VMEM overlaps compute.
// Work swizzle: flat id -> (tile,y) such that same-expert tiles (shared
// weight slab) are consecutive on one XCD (id%8 = XCD heuristic).
// ---------------------------------------------------------------------------
__global__ __launch_bounds__(256, 2) void gateup_kernel(
    const short* __restrict__ x_buf,
    const float* __restrict__ gate,
    const float* __restrict__ up,
    const int* __restrict__ tile_expert,
    const int* __restrict__ tile_row0,
    const int* __restrict__ n_tiles,
    __hip_bfloat16* __restrict__ h_buf) {
    // swizzle: 960 blocks, 120 consecutive work items per XCD
    int id = blockIdx.x;
    int W = (id & 7) * 120 + (id >> 3);
    int tile = W % MAX_TILES;       // tiles consecutive within an XCD's range
    int ycol = W / MAX_TILES;       // 0..5
    if (tile >= *n_tiles) return;
    __shared__ short sA[128 * RS];
    __shared__ short sG[128 * RS];
    __shared__ short sU[128 * RS];
    int e = tile_expert[tile];
    int row0 = tile_row0[tile];
    int col0 = ycol * 128;  // in I
    int tid = threadIdx.x;
    int wave = tid >> 6, lane = tid & 63, quad = lane >> 4, r16 = lane & 15;
    int m0w = (wave >> 1) * 64, n0w = (wave & 1) * 64;
    int srow = tid >> 2;          // staging: 0..63
    int scol = (tid & 3) * 8;     // elem offset in K-chunk

    f32x4 accG[4][4], accU[4][4];
#pragma unroll
    for (int i = 0; i < 4; ++i)
#pragma unroll
        for (int j = 0; j < 4; ++j) {
            accG[i][j] = (f32x4){0.f, 0.f, 0.f, 0.f};
            accU[i][j] = (f32x4){0.f, 0.f, 0.f, 0.f};
        }

    const size_t gbase = ((size_t)e * I_N + col0) * H_N;

    bf16x8 pa[2];
    f32x8 pg[2], pu[2];
#pragma unroll
    for (int r = 0; r < 2; ++r) {       // prefetch iter 0
        int row = r * 64 + srow;
        pa[r] = *(const bf16x8*)(x_buf + (size_t)(row0 + row) * H_N + scol);
        pg[r] = *(const f32x8*)(gate + gbase + (size_t)row * H_N + scol);
        pu[r] = *(const f32x8*)(up + gbase + (size_t)row * H_N + scol);
    }

#pragma unroll 1
    for (int k0 = 0; k0 < H_N; k0 += 32) {
        __syncthreads();  // prior iter's frag reads done before overwrite
#pragma unroll
        for (int r = 0; r < 2; ++r) {
            int row = r * 64 + srow;
            *(bf16x8*)&sA[row * RS + scol] = pa[r];
            *(bf16x8*)&sG[row * RS + scol] = cvt8(pg[r]);
            *(bf16x8*)&sU[row * RS + scol] = cvt8(pu[r]);
        }
        __syncthreads();
        if (k0 + 32 < H_N) {            // prefetch iter k+1 (flies under MFMA)
            int kn = k0 + 32;
#pragma unroll
            for (int r = 0; r < 2; ++r) {
                int row = r * 64 + srow;
                pa[r] = *(const bf16x8*)(x_buf + (size_t)(row0 + row) * H_N + kn + scol);
                pg[r] = *(const f32x8*)(gate + gbase + (size_t)row * H_N + kn + scol);
                pu[r] = *(const f32x8*)(up + gbase + (size_t)row * H_N + kn + scol);
            }
        }
        bf16x8 af[4], bg[4], bu[4];
#pragma unroll
        for (int mi = 0; mi < 4; ++mi)
            af[mi] = *(const bf16x8*)&sA[(m0w + mi * 16 + r16) * RS + quad * 8];
#pragma unroll
        for (int ni = 0; ni < 4; ++ni) {
            bg[ni] = *(const bf16x8*)&sG[(n0w + ni * 16 + r16) * RS + quad * 8];
            bu[ni] = *(const bf16x8*)&sU[(n0w + ni * 16 + r16) * RS + quad * 8];
        }
#pragma unroll
        for (int mi = 0; mi < 4; ++mi)
#pragma unroll
            for (int ni = 0; ni < 4; ++ni) {
                accG[mi][ni] = __builtin_amdgcn_mfma_f32_16x16x32_bf16(af[mi], bg[ni], accG[mi][ni], 0, 0, 0);
                accU[mi][ni] = __builtin_amdgcn_mfma_f32_16x16x32_bf16(af[mi], bu[ni], accU[mi][ni], 0, 0, 0);
            }
    }
    // C/D layout: col(n)=lane&15, row(m)=quad*4+reg  [verified round 2]
#pragma unroll
    for (int mi = 0; mi < 4; ++mi)
#pragma unroll
        for (int ni = 0; ni < 4; ++ni)
#pragma unroll
            for (int r = 0; r < 4; ++r) {
                int m = m0w + mi * 16 + quad * 4 + r;
                int n = col0 + n0w + ni * 16 + r16;
                float g = accG[mi][ni][r], u = accU[mi][ni][r];
                float hval = g * u / (1.0f + __expf(-g));
                h_buf[(size_t)(row0 + m) * I_N + n] = __float2bfloat16(hval);
            }
}

// ---------------------------------------------------------------------------
// Kernel 4: down GEMM. 128x128 tile, wave 64x64, BK=32, K=I=768. Same
// prefetch pipeline + swizzle. Output bf16 into d_buf.
// ---------------------------------------------------------------------------
__global__ __launch_bounds__(256, 2) void down_kernel(
    const __hip_bfloat16* __restrict__ h_buf,
    const float* __restrict__ down,
    const int* __restrict__ tile_expert,
    const int* __restrict__ tile_row0,
    const int* __restrict__ n_tiles,
    short* __restrict__ d_buf) {
    // swizzle: 1280 blocks, 160 consecutive work items per XCD
    int id = blockIdx.x;
    int W = (id & 7) * 160 + (id >> 3);
    int tile = W % MAX_TILES;
    int ycol = W / MAX_TILES;       // 0..7
    if (tile >= *n_tiles) return;
    __shared__ short sA[128 * RS];
    __shared__ short sB[128 * RS];
    int e = tile_expert[tile];
    int row0 = tile_row0[tile];
    int col0 = ycol * 128;  // in H
    int tid = threadIdx.x;
    int wave = tid >> 6, lane = tid & 63, quad = lane >> 4, r16 = lane & 15;
    int m0w = (wave >> 1) * 64, n0w = (wave & 1) * 64;
    int srow = tid >> 2;
    int scol = (tid & 3) * 8;

    f32x4 acc[4][4];
#pragma unroll
    for (int i = 0; i < 4; ++i)
#pragma unroll
        for (int j = 0; j < 4; ++j) acc[i][j] = (f32x4){0.f, 0.f, 0.f, 0.f};

    const short* hb = (const short*)h_buf;
    const size_t dbase = ((size_t)e * H_N + col0) * I_N;

    bf16x8 pa[2];
    f32x8 pb[2];
#pragma unroll
    for (int r = 0; r < 2; ++r) {       // prefetch iter 0
        int row = r * 64 + srow;
        pa[r] = *(const bf16x8*)(hb + (size_t)(row0 + row) * I_N + scol);
        pb[r] = *(const f32x8*)(down + dbase + (size_t)row * I_N + scol);
    }

#pragma unroll 1
    for (int k0 = 0; k0 < I_N; k0 += 32) {
        __syncthreads();
#pragma unroll
        for (int r = 0; r < 2; ++r) {
            int row = r * 64 + srow;
            *(bf16x8*)&sA[row * RS + scol] = pa[r];
            *(bf16x8*)&sB[row * RS + scol] = cvt8(pb[r]);
        }
        __syncthreads();
        if (k0 + 32 < I_N) {
            int kn = k0 + 32;
#pragma unroll
            for (int r = 0; r < 2; ++r) {
                int row = r * 64 + srow;
                pa[r] = *(const bf16x8*)(hb + (size_t)(row0 + row) * I_N + kn + scol);
                pb[r] = *(const f32x8*)(down + dbase + (size_t)row * I_N + kn + scol);
            }
        }
        bf16x8 af[4], bf[4];
#pragma unroll
        for (int mi = 0; mi < 4; ++mi)
            af[mi] = *(const bf16x8*)&sA[(m0w + mi * 16 + r16) * RS + quad * 8];
#pragma unroll
        for (int ni = 0; ni < 4; ++ni)
            bf[ni] = *(const bf16x8*)&sB[(n0w + ni * 16 + r16) * RS + quad * 8];
#pragma unroll
        for (int mi = 0; mi < 4; ++mi)
#pragma unroll
            for (int ni = 0; ni < 4; ++ni)
                acc[mi][ni] = __builtin_amdgcn_mfma_f32_16x16x32_bf16(af[mi], bf[ni], acc[mi][ni], 0, 0, 0);
    }
#pragma unroll
    for (int mi = 0; mi < 4; ++mi)
#pragma unroll
        for (int ni = 0; ni < 4; ++ni)
#pragma unroll
            for (int r = 0; r < 4; ++r) {
                int m = m0w + mi * 16 + quad * 4 + r;
                int n = col0 + n0w + ni * 16 + r16;
                unsigned u = __float_as_uint(acc[mi][ni][r]) + 0x8000u;
                d_buf[(size_t)(row0 + m) * H_N + n] = (short)(u >> 16);
            }
}

// ---------------------------------------------------------------------------
// Kernel 5: combine. out[t,h] = sum_k rw[t,k] * d_buf[pair_slot[t,k], h].
// ---------------------------------------------------------------------------
__global__ __launch_bounds__(256) void combine_kernel(
    const short* __restrict__ d_buf,
    const int* __restrict__ pair_slot,
    const float* __restrict__ rw,
    float* __restrict__ out) {
    int idx = blockIdx.x * blockDim.x + threadIdx.x;
    int t = idx >> 10;          // H_N = 1024
    int h = idx & (H_N - 1);
    float acc = 0.f;
#pragma unroll
    for (int k = 0; k < K_N; ++k) {
        int slot = pair_slot[t * K_N + k];
        float w = rw[t * K_N + k];
        acc += w * bf2f(d_buf[(size_t)slot * H_N + h]);
    }
    out[idx] = acc;
}

// ---------------------------------------------------------------------------
extern "C" void kernel_launch(void* const* d_in, const int* in_sizes, int n_in,
                              void* d_out, int out_size, void* d_ws, size_t ws_size,
                              hipStream_t stream) {
    const float* hs   = (const float*)d_in[0];
    const float* rw   = (const float*)d_in[1];
    const int*   sel  = (const int*)d_in[2];
    const float* gate = (const float*)d_in[3];
    const float* up   = (const float*)d_in[4];
    const float* down = (const float*)d_in[5];
    float* out = (float*)d_out;

    // Workspace carve-up (256B-aligned). x_buf reused as d_buf (both
    // MAX_SLOTS x H_N bf16; x dead after gateup). Total ~74 MB.
    char* ws = (char*)d_ws;
    int* slot_token  = (int*)ws;  ws += ((size_t)MAX_SLOTS * 4 + 255) / 256 * 256;
    int* pair_slot   = (int*)ws;  ws += ((size_t)NPAIRS * 4 + 255) / 256 * 256;
    int* tile_expert = (int*)ws;  ws += ((size_t)MAX_TILES * 4 + 255) / 256 * 256;
    int* tile_row0   = (int*)ws;  ws += ((size_t)MAX_TILES * 4 + 255) / 256 * 256;
    int* n_tiles     = (int*)ws;  ws += 256;
    short* x_buf = (short*)ws;    ws += ((size_t)MAX_SLOTS * H_N * 2 + 255) / 256 * 256;
    __hip_bfloat16* h_buf = (__hip_bfloat16*)ws;
    short* d_buf = x_buf;  // reuse

    hipMemsetAsync(slot_token, 0xFF, (size_t)MAX_SLOTS * 4, stream);
    route_kernel<<<1, 256, 0, stream>>>(sel, slot_token, pair_slot,
                                        tile_expert, tile_row0, n_tiles);
    gather_kernel<<<(MAX_SLOTS * H_N / 4) / 256, 256, 0, stream>>>(hs, slot_token, x_buf);

    gateup_kernel<<<MAX_TILES * (I_N / 128), 256, 0, stream>>>(
        x_buf, gate, up, tile_expert, tile_row0, n_tiles, h_buf);

    down_kernel<<<MAX_TILES * (H_N / 128), 256, 0, stream>>>(
        h_buf, down, tile_expert, tile_row0, n_tiles, d_buf);

    combine_kernel<<<(T_N * H_N) / 256, 256, 0, stream>>>(d_buf, pair_slot,
                                                          rw, out);
}